// Round 7
// baseline (1715.797 us; speedup 1.0000x reference)
//
#include <hip/hip_runtime.h>
#include <hip/hip_bf16.h>
#include <cstdint>
#include <cstddef>

#define DIM 5120
#define NH 40
#define HD 128
#define S_LEN 4096
#define L_LEN 512
#define CBATCH 2            // 2*B (cond + uncond)
#define MQ (CBATCH*S_LEN)   // 8192 rows of hidden
#define ML (CBATCH*L_LEN)   // 1024 rows of context

typedef unsigned short ushort_t;
typedef __bf16 bf16x8 __attribute__((ext_vector_type(8)));
typedef float f32x4 __attribute__((ext_vector_type(4)));
typedef float f32x16 __attribute__((ext_vector_type(16)));

__device__ __forceinline__ ushort_t f2bf(float f) {
  union { float f; unsigned u; } c; c.f = f;
  unsigned r = c.u + 0x7fffu + ((c.u >> 16) & 1u);
  return (ushort_t)(r >> 16);
}

__device__ __forceinline__ void load_lds16(const void* g, void* l) {
  __builtin_amdgcn_global_load_lds(
      (const __attribute__((address_space(1))) void*)g,
      (__attribute__((address_space(3))) void*)l, 16, 0, 0);
}

// ---------------- fp32 -> bf16 convert ----------------
__global__ __launch_bounds__(256) void cvt_f32_bf16(const float* __restrict__ in,
                                                    ushort_t* __restrict__ out, int n4) {
  int i = blockIdx.x * 256 + threadIdx.x;
  if (i >= n4) return;
  float4 v = *(const float4*)(in + 4ull * (size_t)i);
  ushort4 o;
  o.x = f2bf(v.x); o.y = f2bf(v.y); o.z = f2bf(v.z); o.w = f2bf(v.w);
  *(ushort4*)(out + 4ull * (size_t)i) = o;
}

// ============ 256x256 GEMM, BK=32, 64 KiB LDS -> 2 blocks/CU ============
// 8 waves (2M x 4N), wave tile 128x64, 32x32x16 MFMA (2 k-steps/tile).
// LDS: 2 buffers x 32 KiB (regions: B 16K | A 16K; rows x 32 cols, 64 B/row).
// Per tile: issue 4 gload_lds for t+1 into buf^1; 12 ds_read_b128 + 16 MFMA
// (compiler-scheduled); vmcnt(0) + one s_barrier. With 2 resident blocks/CU,
// one block's MFMA covers the other's staging stall (TLP, m114 mechanism).
// Swizzle: byte bits[5:4] ^= row bits[4:3]; linear gload dest, pre-swizzled src.
template <int OUT_F32>
__global__ __launch_bounds__(512, 2) void gemm_bt8(const ushort_t* __restrict__ A,
                                                   const ushort_t* __restrict__ W,
                                                   const float* __restrict__ bias,
                                                   void* __restrict__ Cout,
                                                   int M, int N, int K) {
  __shared__ ushort_t lds[32768];   // 64 KiB
  char* ldsc = (char*)lds;
  const int tid = threadIdx.x;
  const int lane = tid & 63, w = tid >> 6;
  const int l31 = lane & 31, hi = lane >> 5;
  const int wm = w >> 2, wn = w & 3;          // 2M x 4N waves
  const int ntn = N >> 8;
  const int nwg = gridDim.x;
  int bid = blockIdx.x;
  bid = (bid & 7) * (nwg >> 3) + (bid >> 3);  // XCD swizzle (nwg % 8 == 0)
  const int tm = bid / ntn, tn = bid % ntn;
  const size_t m0 = (size_t)tm * 256, n0 = (size_t)tn * 256;
  const ushort_t* Ab = A + m0 * (size_t)K;
  const ushort_t* Bb = W + n0 * (size_t)K;
  const int NT = K >> 5;

  // staging (write side): linear LDS dest, pre-swizzled global source chunk
  const int srow = tid >> 2;                       // region row 0-127
  const int sgq  = (tid & 3) ^ ((tid >> 5) & 3);   // swizzled 16B-chunk
  const size_t rb0 = (size_t)srow * K + (size_t)sgq * 8;   // rows 0-127
  const size_t rb1 = rb0 + (size_t)128 * K;                // rows 128-255
  const int d0 = tid * 16;

  // read-side bases (32x32x16 frags: 32 lanes <-> 32 rows; hi = 16B k-half)
  int aBase[4], aSw[4], bBase[2], bSw[2];
#pragma unroll
  for (int mt = 0; mt < 4; ++mt) {
    int row = wm * 128 + mt * 32 + l31;
    aBase[mt] = 16384 + row * 64;
    aSw[mt]   = (row & 24) << 1;
  }
#pragma unroll
  for (int nt = 0; nt < 2; ++nt) {
    int row = wn * 64 + nt * 32 + l31;
    bBase[nt] = row * 64;
    bSw[nt]   = (row & 24) << 1;
  }
  const int hib = hi << 4;

  auto STAGE = [&](int tIdx, int buf) {
#pragma unroll
    for (int j = 0; j < 2; ++j) {          // j: B, A
      const ushort_t* gsrc = (j ? Ab : Bb) + (size_t)tIdx * 32;
      char* db = ldsc + buf * 32768 + j * 16384;
      load_lds16(gsrc + rb0, db + d0);
      load_lds16(gsrc + rb1, db + 8192 + d0);
    }
  };

  f32x16 acc[4][2];
#pragma unroll
  for (int mt = 0; mt < 4; ++mt)
#pragma unroll
    for (int nt = 0; nt < 2; ++nt) acc[mt][nt] = 0.f;

  // prologue: tile 0 into buf 0
  STAGE(0, 0);
  asm volatile("s_waitcnt vmcnt(0)" ::: "memory");
  __builtin_amdgcn_s_barrier();

  int buf = 0;
  for (int t = 0; t < NT; ++t) {
    if (t + 1 < NT) STAGE(t + 1, buf ^ 1);
    const int bb = buf * 32768;

    bf16x8 bfr[2][2];
#pragma unroll
    for (int nt = 0; nt < 2; ++nt)
#pragma unroll
      for (int ks = 0; ks < 2; ++ks)
        bfr[nt][ks] = *(const bf16x8*)(ldsc + bb + bBase[nt] +
                                       (((ks << 5) | hib) ^ bSw[nt]));
    __builtin_amdgcn_s_setprio(1);
#pragma unroll
    for (int mt = 0; mt < 4; ++mt) {
      bf16x8 af[2];
#pragma unroll
      for (int ks = 0; ks < 2; ++ks)
        af[ks] = *(const bf16x8*)(ldsc + bb + aBase[mt] +
                                  (((ks << 5) | hib) ^ aSw[mt]));
#pragma unroll
      for (int nt = 0; nt < 2; ++nt)
#pragma unroll
        for (int ks = 0; ks < 2; ++ks)
          acc[mt][nt] = __builtin_amdgcn_mfma_f32_32x32x16_bf16(af[ks], bfr[nt][ks],
                                                                acc[mt][nt], 0, 0, 0);
    }
    __builtin_amdgcn_s_setprio(0);

    asm volatile("s_waitcnt vmcnt(0)" ::: "memory");   // tile t+1 landed
    __builtin_amdgcn_s_barrier();                      // all waves done with buf
    buf ^= 1;
  }

  // epilogue: 32x32 C/D layout col=lane&31, row=(reg&3)+8*(reg>>2)+4*hi
#pragma unroll
  for (int mt = 0; mt < 4; ++mt) {
#pragma unroll
    for (int nt = 0; nt < 2; ++nt) {
      size_t gn = n0 + wn * 64 + nt * 32 + l31;
      size_t gmb = m0 + wm * 128 + mt * 32 + 4 * hi;
      float bn = bias[gn];
#pragma unroll
      for (int r = 0; r < 16; ++r) {
        size_t gm = gmb + (r & 3) + 8 * (r >> 2);
        float v = acc[mt][nt][r] + bn;
        if (OUT_F32) ((float*)Cout)[gm * (size_t)N + gn] = v;
        else         ((ushort_t*)Cout)[gm * (size_t)N + gn] = f2bf(v);
      }
    }
  }
  (void)M;
}

// ---------------- 128x128 GEMM (m97 structure) for the small KV GEMM ----------------
template <int OUT_F32>
__global__ __launch_bounds__(256) void gemm_bt(const ushort_t* __restrict__ A,
                                               const ushort_t* __restrict__ W,
                                               const float* __restrict__ bias,
                                               void* __restrict__ Cout,
                                               int M, int N, int K) {
  __shared__ ushort_t sA[128 * 32];
  __shared__ ushort_t sB[128 * 32];
  const int tid = threadIdx.x;
  const int w = tid >> 6, lane = tid & 63;
  const int g = lane >> 4, c = lane & 15;
  const int ntn = N >> 7;
  const int nwg = gridDim.x;
  int bid = blockIdx.x;
  bid = (bid & 7) * (nwg >> 3) + (bid >> 3);
  const int tm = bid / ntn, tn = bid % ntn;
  const size_t m0 = (size_t)tm * 128, n0 = (size_t)tn * 128;
  const int wr = (w >> 1) * 64, wc = (w & 1) * 64;

  f32x4 acc[4][4] = {};

  const ushort_t* Abase = A + m0 * (size_t)K;
  const ushort_t* Bbase = W + n0 * (size_t)K;

  for (int k0 = 0; k0 < K; k0 += 32) {
    __syncthreads();
#pragma unroll
    for (int i = 0; i < 2; ++i) {
      int gid = i * 256 + tid;
      int row = gid >> 2, colE = (gid & 3) << 3;
      load_lds16(Abase + (size_t)row * K + k0 + colE, sA + i * 2048 + w * 512);
      load_lds16(Bbase + (size_t)row * K + k0 + colE, sB + i * 2048 + w * 512);
    }
    __syncthreads();
    bf16x8 a[4], b[4];
#pragma unroll
    for (int m = 0; m < 4; ++m)
      a[m] = *(const bf16x8*)(sA + (wr + m * 16 + c) * 32 + g * 8);
#pragma unroll
    for (int n = 0; n < 4; ++n)
      b[n] = *(const bf16x8*)(sB + (wc + n * 16 + c) * 32 + g * 8);
#pragma unroll
    for (int m = 0; m < 4; ++m)
#pragma unroll
      for (int n = 0; n < 4; ++n)
        acc[m][n] = __builtin_amdgcn_mfma_f32_16x16x32_bf16(a[m], b[n], acc[m][n], 0, 0, 0);
  }

#pragma unroll
  for (int m = 0; m < 4; ++m) {
#pragma unroll
    for (int n = 0; n < 4; ++n) {
      size_t gm = m0 + wr + m * 16 + g * 4;
      size_t gn = n0 + wc + n * 16 + c;
      float bn = bias[gn];
#pragma unroll
      for (int r = 0; r < 4; ++r) {
        float v = acc[m][n][r] + bn;
        if (OUT_F32) ((float*)Cout)[(gm + r) * (size_t)N + gn] = v;
        else         ((ushort_t*)Cout)[(gm + r) * (size_t)N + gn] = f2bf(v);
      }
    }
  }
}

// ---------------- RMSNorm (in place; optional extra output scale) ----------------
__global__ __launch_bounds__(256) void rmsnorm_rows(ushort_t* __restrict__ x,
                                                    const float* __restrict__ gw,
                                                    int ncols, int stride, float oscale) {
  const int row = blockIdx.x;
  ushort_t* p = x + (size_t)row * stride;
  const int tid = threadIdx.x;
  const int nch = ncols >> 3;
  float ss = 0.f;
  for (int ci = tid; ci < nch; ci += 256) {
    bf16x8 v = *(const bf16x8*)(p + ci * 8);
#pragma unroll
    for (int j = 0; j < 8; ++j) { float f = (float)v[j]; ss += f * f; }
  }
#pragma unroll
  for (int off = 1; off < 64; off <<= 1) ss += __shfl_xor(ss, off);
  __shared__ float sred[4];
  if ((tid & 63) == 0) sred[tid >> 6] = ss;
  __syncthreads();
  float tot = sred[0] + sred[1] + sred[2] + sred[3];
  float inv = rsqrtf(tot / (float)ncols + 1e-6f) * oscale;
  for (int ci = tid; ci < nch; ci += 256) {
    bf16x8 v = *(const bf16x8*)(p + ci * 8);
    bf16x8 ov;
#pragma unroll
    for (int j = 0; j < 8; ++j) {
      float f = (float)v[j];
      ushort_t ob = f2bf(f * inv * gw[ci * 8 + j]);
      ov[j] = *(__bf16*)&ob;
    }
    *(bf16x8*)(p + ci * 8) = ov;
  }
}

// ---------------- V transpose: kv[:, DIM + h*HD + d] -> vt[bh][d][l] ----------------
__global__ __launch_bounds__(256) void transpose_v(const ushort_t* __restrict__ kv,
                                                   ushort_t* __restrict__ vt) {
  const int bh = blockIdx.y, b = bh / NH, h = bh % NH;
  const int l0 = blockIdx.x * 32;
  const ushort_t* src = kv + (size_t)b * L_LEN * (2 * DIM) + DIM + (size_t)h * HD;
  ushort_t* dst = vt + (size_t)bh * HD * L_LEN;
  __shared__ ushort_t tile[32][HD + 16];
  const int tid = threadIdx.x;
#pragma unroll
  for (int i = 0; i < 2; ++i) {
    int gid = i * 256 + tid;
    int r = gid >> 4, ce = (gid & 15) << 3;
    *(bf16x8*)(&tile[r][ce]) = *(const bf16x8*)(src + (size_t)(l0 + r) * (2 * DIM) + ce);
  }
  __syncthreads();
#pragma unroll
  for (int i = 0; i < 2; ++i) {
    int gid = i * 256 + tid;
    int d = gid >> 2, le = (gid & 3) << 3;
    bf16x8 v;
#pragma unroll
    for (int j = 0; j < 8; ++j) v[j] = *(__bf16*)&tile[le + j][d];
    *(bf16x8*)(dst + (size_t)d * L_LEN + l0 + le) = v;
  }
}

// ---------------- fused cross-attention (swapped-QK^T, in-register softmax) ----------
__global__ __launch_bounds__(256) void attn_fwd(const ushort_t* __restrict__ q,
                                                const ushort_t* __restrict__ kv,
                                                const ushort_t* __restrict__ vt,
                                                ushort_t* __restrict__ out) {
  const int bh = blockIdx.y, b = bh / NH, h = bh % NH;
  const int tid = threadIdx.x, w = tid >> 6, lane = tid & 63;
  const int lq = lane & 31, hi = lane >> 5;
  const int qr0 = blockIdx.x * 128 + w * 32;

  const ushort_t* qrow  = q  + ((size_t)b * S_LEN + qr0 + lq) * DIM + (size_t)h * HD + hi * 8;
  const ushort_t* krow  = kv + (size_t)b * L_LEN * (2 * DIM) + (size_t)h * HD
                             + (size_t)lq * (2 * DIM) + hi * 8;
  const ushort_t* vrow  = vt + (size_t)bh * HD * L_LEN + (size_t)lq * L_LEN + hi * 8;

  bf16x8 qf[8];
#pragma unroll
  for (int ks = 0; ks < 8; ++ks) qf[ks] = *(const bf16x8*)(qrow + ks * 16);

  f32x16 o[4];
#pragma unroll
  for (int ch = 0; ch < 4; ++ch) o[ch] = 0.f;
  float m = -1e30f, lsum = 0.f;

  for (int l0 = 0; l0 < L_LEN; l0 += 32) {
    f32x16 sv = 0.f;
#pragma unroll
    for (int ks = 0; ks < 8; ++ks) {
      bf16x8 kf = *(const bf16x8*)(krow + (size_t)l0 * (2 * DIM) + ks * 16);
      sv = __builtin_amdgcn_mfma_f32_32x32x16_bf16(kf, qf[ks], sv, 0, 0, 0);
    }
    float pm = fmaxf(fmaxf(fmaxf(sv[0], sv[1]), fmaxf(sv[2], sv[3])),
                     fmaxf(fmaxf(sv[4], sv[5]), fmaxf(sv[6], sv[7])));
    pm = fmaxf(pm, fmaxf(fmaxf(fmaxf(sv[8], sv[9]), fmaxf(sv[10], sv[11])),
                         fmaxf(fmaxf(sv[12], sv[13]), fmaxf(sv[14], sv[15]))));
    pm = fmaxf(pm, __shfl_xor(pm, 32));
    if (__ballot(pm > m + 8.0f)) {
      float mn = fmaxf(m, pm);
      float al = __builtin_amdgcn_exp2f(m - mn);
      lsum *= al;
      m = mn;
#pragma unroll
      for (int r = 0; r < 16; ++r) {
        float ar = __shfl(al, (r & 3) + 8 * (r >> 2) + 4 * hi);
        o[0][r] *= ar; o[1][r] *= ar; o[2][r] *= ar; o[3][r] *= ar;
      }
    }
    float p[16]; float ls = 0.f;
#pragma unroll
    for (int r = 0; r < 16; ++r) { p[r] = __builtin_amdgcn_exp2f(sv[r] - m); ls += p[r]; }
    ls += __shfl_xor(ls, 32);
    lsum += ls;
    bf16x8 pa[2];
#pragma unroll
    for (int ks = 0; ks < 2; ++ks) {
      unsigned w0 = (unsigned)f2bf(p[8 * ks + 0]) | ((unsigned)f2bf(p[8 * ks + 1]) << 16);
      unsigned w1 = (unsigned)f2bf(p[8 * ks + 2]) | ((unsigned)f2bf(p[8 * ks + 3]) << 16);
      unsigned w2 = (unsigned)f2bf(p[8 * ks + 4]) | ((unsigned)f2bf(p[8 * ks + 5]) << 16);
      unsigned w3 = (unsigned)f2bf(p[8 * ks + 6]) | ((unsigned)f2bf(p[8 * ks + 7]) << 16);
      unsigned e0 = __shfl_xor((int)w0, 32), e1 = __shfl_xor((int)w1, 32);
      unsigned e2 = __shfl_xor((int)w2, 32), e3 = __shfl_xor((int)w3, 32);
      unsigned d0 = hi ? e2 : w0, d1 = hi ? e3 : w1;
      unsigned d2 = hi ? w2 : e0, d3 = hi ? w3 : e1;
      unsigned tmp[4] = {d0, d1, d2, d3};
      pa[ks] = *(const bf16x8*)tmp;
    }
#pragma unroll
    for (int ch = 0; ch < 4; ++ch) {
#pragma unroll
      for (int ks = 0; ks < 2; ++ks) {
        bf16x8 vf = *(const bf16x8*)(vrow + (size_t)ch * 32 * L_LEN + l0 + ks * 16);
        o[ch] = __builtin_amdgcn_mfma_f32_32x32x16_bf16(pa[ks], vf, o[ch], 0, 0, 0);
      }
    }
  }

  float inv[16];
#pragma unroll
  for (int r = 0; r < 16; ++r) {
    float lr = __shfl(lsum, (r & 3) + 8 * (r >> 2) + 4 * hi);
    inv[r] = 1.0f / lr;
  }
  ushort_t* ob = out + ((size_t)b * S_LEN + qr0) * DIM + (size_t)h * HD;
#pragma unroll
  for (int ch = 0; ch < 4; ++ch)
#pragma unroll
    for (int r = 0; r < 16; ++r) {
      int row = (r & 3) + 8 * (r >> 2) + 4 * hi;
      ob[(size_t)row * DIM + ch * 32 + lq] = f2bf(o[ch][r] * inv[r]);
    }
}

// ---------------- host ----------------
extern "C" void kernel_launch(void* const* d_in, const int* in_sizes, int n_in,
                              void* d_out, int out_size, void* d_ws, size_t ws_size,
                              hipStream_t stream) {
  (void)in_sizes; (void)n_in; (void)out_size; (void)ws_size;
  const float* hidden_c = (const float*)d_in[0];
  const float* hidden_u = (const float*)d_in[1];
  const float* ctx_c    = (const float*)d_in[2];
  const float* ctx_u    = (const float*)d_in[3];
  const float* Wq  = (const float*)d_in[4];
  const float* bq  = (const float*)d_in[5];
  const float* Wkv = (const float*)d_in[6];
  const float* bkv = (const float*)d_in[7];
  const float* gq  = (const float*)d_in[8];
  const float* gk  = (const float*)d_in[9];
  const float* Wo  = (const float*)d_in[10];
  const float* bo  = (const float*)d_in[11];

  char* ws = (char*)d_ws;
  size_t off = 0;
  auto alloc = [&](size_t bytes) {
    char* p = ws + off; off += (bytes + 255) & ~(size_t)255; return p;
  };
  ushort_t* hbf  = (ushort_t*)alloc((size_t)MQ * DIM * 2);
  ushort_t* cbf  = (ushort_t*)alloc((size_t)ML * DIM * 2);
  ushort_t* wqb  = (ushort_t*)alloc((size_t)DIM * DIM * 2);
  ushort_t* wkvb = (ushort_t*)alloc((size_t)2 * DIM * DIM * 2);
  ushort_t* kvb  = (ushort_t*)alloc((size_t)ML * 2 * DIM * 2);
  ushort_t* vtb  = (ushort_t*)alloc((size_t)CBATCH * NH * HD * L_LEN * 2);
  ushort_t* qb   = (ushort_t*)d_out;

  auto cvt = [&](const float* in, ushort_t* o, size_t n) {
    int n4 = (int)(n >> 2);
    cvt_f32_bf16<<<dim3((n4 + 255) / 256), dim3(256), 0, stream>>>(in, o, n4);
  };
  cvt(hidden_c, hbf, (size_t)S_LEN * DIM);
  cvt(hidden_u, hbf + (size_t)S_LEN * DIM, (size_t)S_LEN * DIM);
  cvt(ctx_c, cbf, (size_t)L_LEN * DIM);
  cvt(ctx_u, cbf + (size_t)L_LEN * DIM, (size_t)L_LEN * DIM);
  cvt(Wq, wqb, (size_t)DIM * DIM);
  cvt(Wkv, wkvb, (size_t)2 * DIM * DIM);

  // Q = hidden @ Wq^T + bq  (256x256 tiles, BK=32, 2 blocks/CU)
  gemm_bt8<0><<<dim3((MQ / 256) * (DIM / 256)), dim3(512), 0, stream>>>(
      hbf, wqb, bq, (void*)qb, MQ, DIM, DIM);
  // KV = context @ Wkv^T + bkv   [128x128]
  gemm_bt<0><<<dim3((ML / 128) * ((2 * DIM) / 128)), dim3(256), 0, stream>>>(
      cbf, wkvb, bkv, (void*)kvb, ML, 2 * DIM, DIM);
  cvt(Wo, wqb, (size_t)DIM * DIM);

  const float qscale = 0.08838834764831845f * 1.4426950408889634f;
  rmsnorm_rows<<<dim3(MQ), dim3(256), 0, stream>>>(qb, gq, DIM, DIM, qscale);
  rmsnorm_rows<<<dim3(ML), dim3(256), 0, stream>>>(kvb, gk, DIM, 2 * DIM, 1.0f);
  transpose_v<<<dim3(L_LEN / 32, CBATCH * NH), dim3(256), 0, stream>>>(kvb, vtb);

  attn_fwd<<<dim3(S_LEN / 128, CBATCH * NH), dim3(256), 0, stream>>>(qb, kvb, vtb, hbf);

  // out = attn_out @ Wo^T + bo -> d_out (fp32)
  gemm_bt8<1><<<dim3((MQ / 256) * (DIM / 256)), dim3(512), 0, stream>>>(
      hbf, wqb, bo, d_out, MQ, DIM, DIM);
}

// Round 8
// 1431.813 us; speedup vs baseline: 1.1983x; 1.1983x over previous
//
#include <hip/hip_runtime.h>
#include <hip/hip_bf16.h>
#include <cstdint>
#include <cstddef>

#define DIM 5120
#define NH 40
#define HD 128
#define S_LEN 4096
#define L_LEN 512
#define CBATCH 2            // 2*B (cond + uncond)
#define MQ (CBATCH*S_LEN)   // 8192 rows of hidden
#define ML (CBATCH*L_LEN)   // 1024 rows of context

typedef unsigned short ushort_t;
typedef __bf16 bf16x8 __attribute__((ext_vector_type(8)));
typedef float f32x4 __attribute__((ext_vector_type(4)));
typedef float f32x16 __attribute__((ext_vector_type(16)));

__device__ __forceinline__ ushort_t f2bf(float f) {
  union { float f; unsigned u; } c; c.f = f;
  unsigned r = c.u + 0x7fffu + ((c.u >> 16) & 1u);
  return (ushort_t)(r >> 16);
}

__device__ __forceinline__ void load_lds16(const void* g, void* l) {
  __builtin_amdgcn_global_load_lds(
      (const __attribute__((address_space(1))) void*)g,
      (__attribute__((address_space(3))) void*)l, 16, 0, 0);
}

// ---------------- fp32 -> bf16 convert ----------------
__global__ __launch_bounds__(256) void cvt_f32_bf16(const float* __restrict__ in,
                                                    ushort_t* __restrict__ out, int n4) {
  int i = blockIdx.x * 256 + threadIdx.x;
  if (i >= n4) return;
  float4 v = *(const float4*)(in + 4ull * (size_t)i);
  ushort4 o;
  o.x = f2bf(v.x); o.y = f2bf(v.y); o.z = f2bf(v.z); o.w = f2bf(v.w);
  *(ushort4*)(out + 4ull * (size_t)i) = o;
}

// ============ 256x256 8-phase GEMM with 9-region LDS ring (R5, best measured) ============
template <int OUT_F32>
__global__ __launch_bounds__(512, 2) void gemm_bt8(const ushort_t* __restrict__ A,
                                                   const ushort_t* __restrict__ W,
                                                   const float* __restrict__ bias,
                                                   void* __restrict__ Cout,
                                                   int M, int N, int K) {
  __shared__ ushort_t lds[73728];   // 144 KiB = 9 x 16 KiB
  char* ldsc = (char*)lds;
  const int tid = threadIdx.x;
  const int lane = tid & 63, w = tid >> 6;
  const int g = lane >> 4, c = lane & 15;
  const int wm = w >> 2, wn = w & 3;
  const int ntn = N >> 8;
  const int nwg = gridDim.x;
  int bid = blockIdx.x;
  bid = (bid & 7) * (nwg >> 3) + (bid >> 3);   // XCD swizzle (nwg % 8 == 0)
  const int tm = bid / ntn, tn = bid % ntn;
  const size_t m0 = (size_t)tm * 256, n0 = (size_t)tn * 256;
  const ushort_t* Ab = A + m0 * (size_t)K;
  const ushort_t* Bb = W + n0 * (size_t)K;
  const int NT = K >> 6;

  const int srow = tid >> 2;
  const int sgq  = (tid & 3) ^ (((tid >> 5) & 1) << 1);
  const size_t rb0 = (size_t)srow * K + (size_t)sgq * 8;
  const size_t rb1 = rb0 + (size_t)128 * K;
  const int d0 = tid * 16;

  int offA[8], offB[4];
#pragma unroll
  for (int m = 0; m < 8; ++m) {
    int row = wm * 128 + m * 16 + c;
    offA[m] = row * 64 + ((g * 16) ^ ((row & 8) << 2));
  }
#pragma unroll
  for (int n = 0; n < 4; ++n) {
    int row = wn * 64 + n * 16 + c;
    offB[n] = row * 64 + ((g * 16) ^ ((row & 8) << 2));
  }

  auto STAGE = [&](int tIdx, int j, int dOff) {
    const size_t kof = (size_t)tIdx * 64 + (size_t)((j >> 1) << 5);
    const ushort_t* gsrc = ((j & 1) ? Ab : Bb) + kof;
    char* db = ldsc + dOff;
    load_lds16(gsrc + rb0, db + d0);
    load_lds16(gsrc + rb1, db + 8192 + d0);
  };
  auto nx = [](int x) { return (x + 16384 == 147456) ? 0 : x + 16384; };

  f32x4 acc[8][4] = {};

#pragma unroll
  for (int h = 0; h < 8; ++h) STAGE(h >> 2, h & 3, h * 16384);
  asm volatile("s_waitcnt vmcnt(8)" ::: "memory");
  __builtin_amdgcn_s_barrier();

  int rd = 0;
  int sOff = 131072;
  for (int t = 0; t < NT; ++t) {
    const int r0 = rd, r1 = nx(r0), r2 = nx(r1), r3 = nx(r2);
    bf16x8 a[4], a2[4], b[4];
#pragma unroll
    for (int m = 0; m < 4; ++m) a[m] = *(const bf16x8*)(ldsc + r1 + offA[m]);
#pragma unroll
    for (int n = 0; n < 4; ++n) b[n] = *(const bf16x8*)(ldsc + r0 + offB[n]);
    if (t < NT - 2) { STAGE(t + 2, 0, sOff); sOff = nx(sOff); }
    __builtin_amdgcn_s_barrier();
    asm volatile("s_waitcnt lgkmcnt(0)" ::: "memory");
    __builtin_amdgcn_sched_barrier(0);
    __builtin_amdgcn_s_setprio(1);
#pragma unroll
    for (int m = 0; m < 4; ++m)
#pragma unroll
      for (int n = 0; n < 4; ++n)
        acc[m][n] = __builtin_amdgcn_mfma_f32_16x16x32_bf16(a[m], b[n], acc[m][n], 0, 0, 0);
    __builtin_amdgcn_s_setprio(0);
    __builtin_amdgcn_s_barrier();
#pragma unroll
    for (int m = 0; m < 4; ++m) a2[m] = *(const bf16x8*)(ldsc + r1 + offA[4 + m]);
    if (t < NT - 2) { STAGE(t + 2, 1, sOff); sOff = nx(sOff); }
    __builtin_amdgcn_s_barrier();
    asm volatile("s_waitcnt lgkmcnt(0)" ::: "memory");
    __builtin_amdgcn_sched_barrier(0);
    __builtin_amdgcn_s_setprio(1);
#pragma unroll
    for (int m = 0; m < 4; ++m)
#pragma unroll
      for (int n = 0; n < 4; ++n)
        acc[4 + m][n] = __builtin_amdgcn_mfma_f32_16x16x32_bf16(a2[m], b[n], acc[4 + m][n], 0, 0, 0);
    __builtin_amdgcn_s_setprio(0);
    __builtin_amdgcn_s_barrier();
#pragma unroll
    for (int m = 0; m < 4; ++m) a[m] = *(const bf16x8*)(ldsc + r3 + offA[m]);
#pragma unroll
    for (int n = 0; n < 4; ++n) b[n] = *(const bf16x8*)(ldsc + r2 + offB[n]);
    if (t < NT - 2) { STAGE(t + 2, 2, sOff); sOff = nx(sOff); }
    __builtin_amdgcn_s_barrier();
    asm volatile("s_waitcnt lgkmcnt(0)" ::: "memory");
    __builtin_amdgcn_sched_barrier(0);
    __builtin_amdgcn_s_setprio(1);
#pragma unroll
    for (int m = 0; m < 4; ++m)
#pragma unroll
      for (int n = 0; n < 4; ++n)
        acc[m][n] = __builtin_amdgcn_mfma_f32_16x16x32_bf16(a[m], b[n], acc[m][n], 0, 0, 0);
    __builtin_amdgcn_s_setprio(0);
    __builtin_amdgcn_s_barrier();
#pragma unroll
    for (int m = 0; m < 4; ++m) a2[m] = *(const bf16x8*)(ldsc + r3 + offA[4 + m]);
    if (t < NT - 2) { STAGE(t + 2, 3, sOff); sOff = nx(sOff); }
    __builtin_amdgcn_s_barrier();
    asm volatile("s_waitcnt lgkmcnt(0)" ::: "memory");
    __builtin_amdgcn_sched_barrier(0);
    __builtin_amdgcn_s_setprio(1);
#pragma unroll
    for (int m = 0; m < 4; ++m)
#pragma unroll
      for (int n = 0; n < 4; ++n)
        acc[4 + m][n] = __builtin_amdgcn_mfma_f32_16x16x32_bf16(a2[m], b[n], acc[4 + m][n], 0, 0, 0);
    __builtin_amdgcn_s_setprio(0);
    if (t < NT - 2)       asm volatile("s_waitcnt vmcnt(6)" ::: "memory");
    else if (t == NT - 2) asm volatile("s_waitcnt vmcnt(0)" ::: "memory");
    __builtin_amdgcn_s_barrier();
    rd = nx(r3);
  }

#pragma unroll
  for (int m = 0; m < 8; ++m) {
#pragma unroll
    for (int n = 0; n < 4; ++n) {
      size_t gm = m0 + wm * 128 + m * 16 + g * 4;
      size_t gn = n0 + wn * 64 + n * 16 + c;
      float bn = bias[gn];
#pragma unroll
      for (int r = 0; r < 4; ++r) {
        float v = acc[m][n][r] + bn;
        if (OUT_F32) ((float*)Cout)[(gm + r) * (size_t)N + gn] = v;
        else         ((ushort_t*)Cout)[(gm + r) * (size_t)N + gn] = f2bf(v);
      }
    }
  }
  (void)M;
}

// ---------------- 128x128 GEMM (m97 structure) for the small KV GEMM ----------------
template <int OUT_F32>
__global__ __launch_bounds__(256) void gemm_bt(const ushort_t* __restrict__ A,
                                               const ushort_t* __restrict__ W,
                                               const float* __restrict__ bias,
                                               void* __restrict__ Cout,
                                               int M, int N, int K) {
  __shared__ ushort_t sA[128 * 32];
  __shared__ ushort_t sB[128 * 32];
  const int tid = threadIdx.x;
  const int w = tid >> 6, lane = tid & 63;
  const int g = lane >> 4, c = lane & 15;
  const int ntn = N >> 7;
  const int nwg = gridDim.x;
  int bid = blockIdx.x;
  bid = (bid & 7) * (nwg >> 3) + (bid >> 3);
  const int tm = bid / ntn, tn = bid % ntn;
  const size_t m0 = (size_t)tm * 128, n0 = (size_t)tn * 128;
  const int wr = (w >> 1) * 64, wc = (w & 1) * 64;

  f32x4 acc[4][4] = {};

  const ushort_t* Abase = A + m0 * (size_t)K;
  const ushort_t* Bbase = W + n0 * (size_t)K;

  for (int k0 = 0; k0 < K; k0 += 32) {
    __syncthreads();
#pragma unroll
    for (int i = 0; i < 2; ++i) {
      int gid = i * 256 + tid;
      int row = gid >> 2, colE = (gid & 3) << 3;
      load_lds16(Abase + (size_t)row * K + k0 + colE, sA + i * 2048 + w * 512);
      load_lds16(Bbase + (size_t)row * K + k0 + colE, sB + i * 2048 + w * 512);
    }
    __syncthreads();
    bf16x8 a[4], b[4];
#pragma unroll
    for (int m = 0; m < 4; ++m)
      a[m] = *(const bf16x8*)(sA + (wr + m * 16 + c) * 32 + g * 8);
#pragma unroll
    for (int n = 0; n < 4; ++n)
      b[n] = *(const bf16x8*)(sB + (wc + n * 16 + c) * 32 + g * 8);
#pragma unroll
    for (int m = 0; m < 4; ++m)
#pragma unroll
      for (int n = 0; n < 4; ++n)
        acc[m][n] = __builtin_amdgcn_mfma_f32_16x16x32_bf16(a[m], b[n], acc[m][n], 0, 0, 0);
  }

#pragma unroll
  for (int m = 0; m < 4; ++m) {
#pragma unroll
    for (int n = 0; n < 4; ++n) {
      size_t gm = m0 + wr + m * 16 + g * 4;
      size_t gn = n0 + wc + n * 16 + c;
      float bn = bias[gn];
#pragma unroll
      for (int r = 0; r < 4; ++r) {
        float v = acc[m][n][r] + bn;
        if (OUT_F32) ((float*)Cout)[(gm + r) * (size_t)N + gn] = v;
        else         ((ushort_t*)Cout)[(gm + r) * (size_t)N + gn] = f2bf(v);
      }
    }
  }
}

// ---------------- RMSNorm (in place; optional extra output scale) ----------------
__global__ __launch_bounds__(256) void rmsnorm_rows(ushort_t* __restrict__ x,
                                                    const float* __restrict__ gw,
                                                    int ncols, int stride, float oscale) {
  const int row = blockIdx.x;
  ushort_t* p = x + (size_t)row * stride;
  const int tid = threadIdx.x;
  const int nch = ncols >> 3;
  float ss = 0.f;
  for (int ci = tid; ci < nch; ci += 256) {
    bf16x8 v = *(const bf16x8*)(p + ci * 8);
#pragma unroll
    for (int j = 0; j < 8; ++j) { float f = (float)v[j]; ss += f * f; }
  }
#pragma unroll
  for (int off = 1; off < 64; off <<= 1) ss += __shfl_xor(ss, off);
  __shared__ float sred[4];
  if ((tid & 63) == 0) sred[tid >> 6] = ss;
  __syncthreads();
  float tot = sred[0] + sred[1] + sred[2] + sred[3];
  float inv = rsqrtf(tot / (float)ncols + 1e-6f) * oscale;
  for (int ci = tid; ci < nch; ci += 256) {
    bf16x8 v = *(const bf16x8*)(p + ci * 8);
    bf16x8 ov;
#pragma unroll
    for (int j = 0; j < 8; ++j) {
      float f = (float)v[j];
      ushort_t ob = f2bf(f * inv * gw[ci * 8 + j]);
      ov[j] = *(__bf16*)&ob;
    }
    *(bf16x8*)(p + ci * 8) = ov;
  }
}

// ---------------- V transpose: kv[:, DIM + h*HD + d] -> vt[bh][d][l] ----------------
__global__ __launch_bounds__(256) void transpose_v(const ushort_t* __restrict__ kv,
                                                   ushort_t* __restrict__ vt) {
  const int bh = blockIdx.y, b = bh / NH, h = bh % NH;
  const int l0 = blockIdx.x * 32;
  const ushort_t* src = kv + (size_t)b * L_LEN * (2 * DIM) + DIM + (size_t)h * HD;
  ushort_t* dst = vt + (size_t)bh * HD * L_LEN;
  __shared__ ushort_t tile[32][HD + 16];
  const int tid = threadIdx.x;
#pragma unroll
  for (int i = 0; i < 2; ++i) {
    int gid = i * 256 + tid;
    int r = gid >> 4, ce = (gid & 15) << 3;
    *(bf16x8*)(&tile[r][ce]) = *(const bf16x8*)(src + (size_t)(l0 + r) * (2 * DIM) + ce);
  }
  __syncthreads();
#pragma unroll
  for (int i = 0; i < 2; ++i) {
    int gid = i * 256 + tid;
    int d = gid >> 2, le = (gid & 3) << 3;
    bf16x8 v;
#pragma unroll
    for (int j = 0; j < 8; ++j) v[j] = *(__bf16*)&tile[le + j][d];
    *(bf16x8*)(dst + (size_t)d * L_LEN + l0 + le) = v;
  }
}

// ---------------- fused cross-attention: LDS-staged K/V, swapped-QK^T ----------
// grid (S_LEN/128, CBATCH*NH), 4 waves, 32 q-rows/wave. Per 32-l tile the block
// stages K (8KB) + V (8KB) coalesced into double-buffered LDS slab layout
// [slab = elem/8][row][16B]; all 4 waves share. Reg-staged (global->reg->ds_write)
// issued for t+1 before tile t's compute; vmcnt(0)+1 barrier per tile.
__global__ __launch_bounds__(256) void attn_fwd(const ushort_t* __restrict__ q,
                                                const ushort_t* __restrict__ kv,
                                                const ushort_t* __restrict__ vt,
                                                ushort_t* __restrict__ out) {
  const int bh = blockIdx.y, b = bh / NH, h = bh % NH;
  const int tid = threadIdx.x, w = tid >> 6, lane = tid & 63;
  const int lq = lane & 31, hi = lane >> 5;
  const int qr0 = blockIdx.x * 128 + w * 32;

  __shared__ ushort_t sK[2][4096];   // [buf][16 slabs][32 l][8k] : 8KB each
  __shared__ ushort_t sV[2][4096];   // [buf][4 slabs][128 d][8l] : 8KB each

  // ---- staging sources (per thread)
  // K: thread t -> l = t>>3, kchunk c = t&7 (16 k = 32B); coalesced 256B/row
  const int skl = tid >> 3, skc = tid & 7;
  const ushort_t* kgsrc = kv + ((size_t)b * L_LEN + skl) * (2 * DIM)
                             + (size_t)h * HD + skc * 16;
  ushort_t* kd0 = &sK[0][(skc * 2) * 256 + skl * 8];       // slab stride 512B = 256 elems
  ushort_t* kd1 = &sK[0][(skc * 2 + 1) * 256 + skl * 8];
  // V: thread t -> d = t>>1, lhalf = t&1 (16 l = 32B); 64B/row
  const int svd = tid >> 1, svh = tid & 1;
  const ushort_t* vgsrc = vt + (size_t)bh * HD * L_LEN + (size_t)svd * L_LEN + svh * 16;
  ushort_t* vd0 = &sV[0][(svh * 2) * 1024 + svd * 8];      // slab stride 2048B = 1024 elems
  ushort_t* vd1 = &sV[0][(svh * 2 + 1) * 1024 + svd * 8];

  const ushort_t* qrow = q + ((size_t)b * S_LEN + qr0 + lq) * DIM + (size_t)h * HD + hi * 8;
  bf16x8 qf[8];
#pragma unroll
  for (int ks = 0; ks < 8; ++ks) qf[ks] = *(const bf16x8*)(qrow + ks * 16);

  f32x16 o[4];
#pragma unroll
  for (int ch = 0; ch < 4; ++ch) o[ch] = 0.f;
  float m = -1e30f, lsum = 0.f;

  // prologue: stage tile 0 into buf 0
  {
    uint4 ka = *(const uint4*)kgsrc;
    uint4 kb = *(const uint4*)(kgsrc + 8);
    uint4 va = *(const uint4*)vgsrc;
    uint4 vb = *(const uint4*)(vgsrc + 8);
    *(uint4*)kd0 = ka; *(uint4*)kd1 = kb;
    *(uint4*)vd0 = va; *(uint4*)vd1 = vb;
  }
  __syncthreads();

  const int NT = L_LEN / 32;
  int buf = 0;
  for (int t = 0; t < NT; ++t) {
    // issue next tile's global loads early (latency hidden under compute)
    uint4 ka, kb, va, vb;
    if (t + 1 < NT) {
      const ushort_t* kg = kgsrc + (size_t)(t + 1) * 32 * (2 * DIM);
      const ushort_t* vg = vgsrc + (t + 1) * 32;
      ka = *(const uint4*)kg; kb = *(const uint4*)(kg + 8);
      va = *(const uint4*)vg; vb = *(const uint4*)(vg + 8);
    }

    const ushort_t* kbuf = sK[buf];
    const ushort_t* vbuf = sV[buf];

    // ---- QK^T (swapped): lane holds col q, 16 l-rows
    f32x16 sv = 0.f;
#pragma unroll
    for (int ks = 0; ks < 8; ++ks) {
      bf16x8 kf = *(const bf16x8*)(kbuf + (ks * 2 + hi) * 256 + lq * 8);
      sv = __builtin_amdgcn_mfma_f32_32x32x16_bf16(kf, qf[ks], sv, 0, 0, 0);
    }
    // ---- softmax (in-register, defer-max)
    float pm = fmaxf(fmaxf(fmaxf(sv[0], sv[1]), fmaxf(sv[2], sv[3])),
                     fmaxf(fmaxf(sv[4], sv[5]), fmaxf(sv[6], sv[7])));
    pm = fmaxf(pm, fmaxf(fmaxf(fmaxf(sv[8], sv[9]), fmaxf(sv[10], sv[11])),
                         fmaxf(fmaxf(sv[12], sv[13]), fmaxf(sv[14], sv[15]))));
    pm = fmaxf(pm, __shfl_xor(pm, 32));
    if (__ballot(pm > m + 8.0f)) {
      float mn = fmaxf(m, pm);
      float al = __builtin_amdgcn_exp2f(m - mn);
      lsum *= al;
      m = mn;
#pragma unroll
      for (int r = 0; r < 16; ++r) {
        float ar = __shfl(al, (r & 3) + 8 * (r >> 2) + 4 * hi);
        o[0][r] *= ar; o[1][r] *= ar; o[2][r] *= ar; o[3][r] *= ar;
      }
    }
    float p[16]; float ls = 0.f;
#pragma unroll
    for (int r = 0; r < 16; ++r) { p[r] = __builtin_amdgcn_exp2f(sv[r] - m); ls += p[r]; }
    ls += __shfl_xor(ls, 32);
    lsum += ls;
    // ---- pack P -> A-frags
    bf16x8 pa[2];
#pragma unroll
    for (int ks = 0; ks < 2; ++ks) {
      unsigned w0 = (unsigned)f2bf(p[8 * ks + 0]) | ((unsigned)f2bf(p[8 * ks + 1]) << 16);
      unsigned w1 = (unsigned)f2bf(p[8 * ks + 2]) | ((unsigned)f2bf(p[8 * ks + 3]) << 16);
      unsigned w2 = (unsigned)f2bf(p[8 * ks + 4]) | ((unsigned)f2bf(p[8 * ks + 5]) << 16);
      unsigned w3 = (unsigned)f2bf(p[8 * ks + 6]) | ((unsigned)f2bf(p[8 * ks + 7]) << 16);
      unsigned e0 = __shfl_xor((int)w0, 32), e1 = __shfl_xor((int)w1, 32);
      unsigned e2 = __shfl_xor((int)w2, 32), e3 = __shfl_xor((int)w3, 32);
      unsigned d0 = hi ? e2 : w0, d1 = hi ? e3 : w1;
      unsigned d2 = hi ? w2 : e0, d3 = hi ? w3 : e1;
      unsigned tmp[4] = {d0, d1, d2, d3};
      pa[ks] = *(const bf16x8*)tmp;
    }
    // ---- PV: O[q][d] += P[q][l] * Vt[d][l]
#pragma unroll
    for (int ch = 0; ch < 4; ++ch) {
#pragma unroll
      for (int ks = 0; ks < 2; ++ks) {
        bf16x8 vf = *(const bf16x8*)(vbuf + (ks * 2 + hi) * 1024 + (ch * 32 + lq) * 8);
        o[ch] = __builtin_amdgcn_mfma_f32_32x32x16_bf16(pa[ks], vf, o[ch], 0, 0, 0);
      }
    }

    // ---- write next tile into buf^1 (its readers finished at tile t-1's barrier)
    if (t + 1 < NT) {
      const int nb = buf ^ 1;
      *(uint4*)(kd0 + nb * 4096) = ka; *(uint4*)(kd1 + nb * 4096) = kb;
      *(uint4*)(vd0 + nb * 4096) = va; *(uint4*)(vd1 + nb * 4096) = vb;
    }
    __syncthreads();
    buf ^= 1;
  }

  // ---- epilogue
  float inv[16];
#pragma unroll
  for (int r = 0; r < 16; ++r) {
    float lr = __shfl(lsum, (r & 3) + 8 * (r >> 2) + 4 * hi);
    inv[r] = 1.0f / lr;
  }
  ushort_t* ob = out + ((size_t)b * S_LEN + qr0) * DIM + (size_t)h * HD;
#pragma unroll
  for (int ch = 0; ch < 4; ++ch)
#pragma unroll
    for (int r = 0; r < 16; ++r) {
      int row = (r & 3) + 8 * (r >> 2) + 4 * hi;
      ob[(size_t)row * DIM + ch * 32 + lq] = f2bf(o[ch][r] * inv[r]);
    }
}

// ---------------- host ----------------
extern "C" void kernel_launch(void* const* d_in, const int* in_sizes, int n_in,
                              void* d_out, int out_size, void* d_ws, size_t ws_size,
                              hipStream_t stream) {
  (void)in_sizes; (void)n_in; (void)out_size; (void)ws_size;
  const float* hidden_c = (const float*)d_in[0];
  const float* hidden_u = (const float*)d_in[1];
  const float* ctx_c    = (const float*)d_in[2];
  const float* ctx_u    = (const float*)d_in[3];
  const float* Wq  = (const float*)d_in[4];
  const float* bq  = (const float*)d_in[5];
  const float* Wkv = (const float*)d_in[6];
  const float* bkv = (const float*)d_in[7];
  const float* gq  = (const float*)d_in[8];
  const float* gk  = (const float*)d_in[9];
  const float* Wo  = (const float*)d_in[10];
  const float* bo  = (const float*)d_in[11];

  char* ws = (char*)d_ws;
  size_t off = 0;
  auto alloc = [&](size_t bytes) {
    char* p = ws + off; off += (bytes + 255) & ~(size_t)255; return p;
  };
  ushort_t* hbf  = (ushort_t*)alloc((size_t)MQ * DIM * 2);
  ushort_t* cbf  = (ushort_t*)alloc((size_t)ML * DIM * 2);
  ushort_t* wqb  = (ushort_t*)alloc((size_t)DIM * DIM * 2);
  ushort_t* wkvb = (ushort_t*)alloc((size_t)2 * DIM * DIM * 2);
  ushort_t* kvb  = (ushort_t*)alloc((size_t)ML * 2 * DIM * 2);
  ushort_t* vtb  = (ushort_t*)alloc((size_t)CBATCH * NH * HD * L_LEN * 2);
  ushort_t* qb   = (ushort_t*)d_out;

  auto cvt = [&](const float* in, ushort_t* o, size_t n) {
    int n4 = (int)(n >> 2);
    cvt_f32_bf16<<<dim3((n4 + 255) / 256), dim3(256), 0, stream>>>(in, o, n4);
  };
  cvt(hidden_c, hbf, (size_t)S_LEN * DIM);
  cvt(hidden_u, hbf + (size_t)S_LEN * DIM, (size_t)S_LEN * DIM);
  cvt(ctx_c, cbf, (size_t)L_LEN * DIM);
  cvt(ctx_u, cbf + (size_t)L_LEN * DIM, (size_t)L_LEN * DIM);
  cvt(Wq, wqb, (size_t)DIM * DIM);
  cvt(Wkv, wkvb, (size_t)2 * DIM * DIM);

  // Q = hidden @ Wq^T + bq  (256x256 tiles, 9-region ring)
  gemm_bt8<0><<<dim3((MQ / 256) * (DIM / 256)), dim3(512), 0, stream>>>(
      hbf, wqb, bq, (void*)qb, MQ, DIM, DIM);
  // KV = context @ Wkv^T + bkv   [128x128]
  gemm_bt<0><<<dim3((ML / 128) * ((2 * DIM) / 128)), dim3(256), 0, stream>>>(
      cbf, wkvb, bkv, (void*)kvb, ML, 2 * DIM, DIM);
  cvt(Wo, wqb, (size_t)DIM * DIM);

  const float qscale = 0.08838834764831845f * 1.4426950408889634f;
  rmsnorm_rows<<<dim3(MQ), dim3(256), 0, stream>>>(qb, gq, DIM, DIM, qscale);
  rmsnorm_rows<<<dim3(ML), dim3(256), 0, stream>>>(kvb, gk, DIM, 2 * DIM, 1.0f);
  transpose_v<<<dim3(L_LEN / 32, CBATCH * NH), dim3(256), 0, stream>>>(kvb, vtb);

  attn_fwd<<<dim3(S_LEN / 128, CBATCH * NH), dim3(256), 0, stream>>>(qb, kvb, vtb, hbf);

  // out = attn_out @ Wo^T + bo -> d_out (fp32)
  gemm_bt8<1><<<dim3((MQ / 256) * (DIM / 256)), dim3(512), 0, stream>>>(
      hbf, wqb, bo, d_out, MQ, DIM, DIM);
}

// Round 9
// 1371.351 us; speedup vs baseline: 1.2512x; 1.0441x over previous
//
#include <hip/hip_runtime.h>
#include <hip/hip_bf16.h>
#include <cstdint>
#include <cstddef>

#define DIM 5120
#define NH 40
#define HD 128
#define S_LEN 4096
#define L_LEN 512
#define CBATCH 2            // 2*B (cond + uncond)
#define MQ (CBATCH*S_LEN)   // 8192 rows of hidden
#define ML (CBATCH*L_LEN)   // 1024 rows of context

typedef unsigned short ushort_t;
typedef __bf16 bf16x8 __attribute__((ext_vector_type(8)));
typedef float f32x4 __attribute__((ext_vector_type(4)));
typedef float f32x16 __attribute__((ext_vector_type(16)));

__device__ __forceinline__ ushort_t f2bf(float f) {
  union { float f; unsigned u; } c; c.f = f;
  unsigned r = c.u + 0x7fffu + ((c.u >> 16) & 1u);
  return (ushort_t)(r >> 16);
}

__device__ __forceinline__ void load_lds16(const void* g, void* l) {
  __builtin_amdgcn_global_load_lds(
      (const __attribute__((address_space(1))) void*)g,
      (__attribute__((address_space(3))) void*)l, 16, 0, 0);
}

// ---------------- fp32 -> bf16 convert ----------------
__global__ __launch_bounds__(256) void cvt_f32_bf16(const float* __restrict__ in,
                                                    ushort_t* __restrict__ out, int n4) {
  int i = blockIdx.x * 256 + threadIdx.x;
  if (i >= n4) return;
  float4 v = *(const float4*)(in + 4ull * (size_t)i);
  ushort4 o;
  o.x = f2bf(v.x); o.y = f2bf(v.y); o.z = f2bf(v.z); o.w = f2bf(v.w);
  *(ushort4*)(out + 4ull * (size_t)i) = o;
}

// ============ 256x256 8-phase GEMM core, 9-region LDS ring (R5-proven) ============
// K = DIM = 5120 compile-time. Ab/Bb are pre-offset to the tile's panels.
// m0/n0 only used for C/bias addressing (C has row stride N).
template <int OUT_F32>
__device__ __forceinline__ void gemm_core(const ushort_t* __restrict__ Ab,
                                          const ushort_t* __restrict__ Bb,
                                          const float* __restrict__ bias,
                                          void* __restrict__ Cout,
                                          int N, size_t m0, size_t n0,
                                          char* ldsc) {
  const int tid = threadIdx.x;
  const int lane = tid & 63, w = tid >> 6;
  const int g = lane >> 4, c = lane & 15;
  const int wm = w >> 2, wn = w & 3;
  constexpr int K = DIM;
  constexpr int NT = K >> 6;   // 80

  const int srow = tid >> 2;
  const int sgq  = (tid & 3) ^ (((tid >> 5) & 1) << 1);
  const size_t rb0 = (size_t)srow * K + (size_t)sgq * 8;
  const size_t rb1 = rb0 + (size_t)128 * K;
  const int d0 = tid * 16;

  int offA[8], offB[4];
#pragma unroll
  for (int m = 0; m < 8; ++m) {
    int row = wm * 128 + m * 16 + c;
    offA[m] = row * 64 + ((g * 16) ^ ((row & 8) << 2));
  }
#pragma unroll
  for (int n = 0; n < 4; ++n) {
    int row = wn * 64 + n * 16 + c;
    offB[n] = row * 64 + ((g * 16) ^ ((row & 8) << 2));
  }

  auto STAGE = [&](int tIdx, int j, int dOff) {
    const size_t kof = (size_t)tIdx * 64 + (size_t)((j >> 1) << 5);
    const ushort_t* gsrc = ((j & 1) ? Ab : Bb) + kof;
    char* db = ldsc + dOff;
    load_lds16(gsrc + rb0, db + d0);
    load_lds16(gsrc + rb1, db + 8192 + d0);
  };
  auto nx = [](int x) { return (x + 16384 == 147456) ? 0 : x + 16384; };

  f32x4 acc[8][4] = {};

#pragma unroll
  for (int h = 0; h < 8; ++h) STAGE(h >> 2, h & 3, h * 16384);
  asm volatile("s_waitcnt vmcnt(8)" ::: "memory");
  __builtin_amdgcn_s_barrier();

  int rd = 0;
  int sOff = 131072;
  for (int t = 0; t < NT; ++t) {
    const int r0 = rd, r1 = nx(r0), r2 = nx(r1), r3 = nx(r2);
    bf16x8 a[4], a2[4], b[4];
#pragma unroll
    for (int m = 0; m < 4; ++m) a[m] = *(const bf16x8*)(ldsc + r1 + offA[m]);
#pragma unroll
    for (int n = 0; n < 4; ++n) b[n] = *(const bf16x8*)(ldsc + r0 + offB[n]);
    if (t < NT - 2) { STAGE(t + 2, 0, sOff); sOff = nx(sOff); }
    __builtin_amdgcn_s_barrier();
    asm volatile("s_waitcnt lgkmcnt(0)" ::: "memory");
    __builtin_amdgcn_sched_barrier(0);
    __builtin_amdgcn_s_setprio(1);
#pragma unroll
    for (int m = 0; m < 4; ++m)
#pragma unroll
      for (int n = 0; n < 4; ++n)
        acc[m][n] = __builtin_amdgcn_mfma_f32_16x16x32_bf16(a[m], b[n], acc[m][n], 0, 0, 0);
    __builtin_amdgcn_s_setprio(0);
    __builtin_amdgcn_s_barrier();
#pragma unroll
    for (int m = 0; m < 4; ++m) a2[m] = *(const bf16x8*)(ldsc + r1 + offA[4 + m]);
    if (t < NT - 2) { STAGE(t + 2, 1, sOff); sOff = nx(sOff); }
    __builtin_amdgcn_s_barrier();
    asm volatile("s_waitcnt lgkmcnt(0)" ::: "memory");
    __builtin_amdgcn_sched_barrier(0);
    __builtin_amdgcn_s_setprio(1);
#pragma unroll
    for (int m = 0; m < 4; ++m)
#pragma unroll
      for (int n = 0; n < 4; ++n)
        acc[4 + m][n] = __builtin_amdgcn_mfma_f32_16x16x32_bf16(a2[m], b[n], acc[4 + m][n], 0, 0, 0);
    __builtin_amdgcn_s_setprio(0);
    __builtin_amdgcn_s_barrier();
#pragma unroll
    for (int m = 0; m < 4; ++m) a[m] = *(const bf16x8*)(ldsc + r3 + offA[m]);
#pragma unroll
    for (int n = 0; n < 4; ++n) b[n] = *(const bf16x8*)(ldsc + r2 + offB[n]);
    if (t < NT - 2) { STAGE(t + 2, 2, sOff); sOff = nx(sOff); }
    __builtin_amdgcn_s_barrier();
    asm volatile("s_waitcnt lgkmcnt(0)" ::: "memory");
    __builtin_amdgcn_sched_barrier(0);
    __builtin_amdgcn_s_setprio(1);
#pragma unroll
    for (int m = 0; m < 4; ++m)
#pragma unroll
      for (int n = 0; n < 4; ++n)
        acc[m][n] = __builtin_amdgcn_mfma_f32_16x16x32_bf16(a[m], b[n], acc[m][n], 0, 0, 0);
    __builtin_amdgcn_s_setprio(0);
    __builtin_amdgcn_s_barrier();
#pragma unroll
    for (int m = 0; m < 4; ++m) a2[m] = *(const bf16x8*)(ldsc + r3 + offA[4 + m]);
    if (t < NT - 2) { STAGE(t + 2, 3, sOff); sOff = nx(sOff); }
    __builtin_amdgcn_s_barrier();
    asm volatile("s_waitcnt lgkmcnt(0)" ::: "memory");
    __builtin_amdgcn_sched_barrier(0);
    __builtin_amdgcn_s_setprio(1);
#pragma unroll
    for (int m = 0; m < 4; ++m)
#pragma unroll
      for (int n = 0; n < 4; ++n)
        acc[4 + m][n] = __builtin_amdgcn_mfma_f32_16x16x32_bf16(a2[m], b[n], acc[4 + m][n], 0, 0, 0);
    __builtin_amdgcn_s_setprio(0);
    if (t < NT - 2)       asm volatile("s_waitcnt vmcnt(6)" ::: "memory");
    else if (t == NT - 2) asm volatile("s_waitcnt vmcnt(0)" ::: "memory");
    __builtin_amdgcn_s_barrier();
    rd = nx(r3);
  }

#pragma unroll
  for (int m = 0; m < 8; ++m) {
#pragma unroll
    for (int n = 0; n < 4; ++n) {
      size_t gm = m0 + wm * 128 + m * 16 + g * 4;
      size_t gn = n0 + wn * 64 + n * 16 + c;
      float bn = bias[gn];
#pragma unroll
      for (int r = 0; r < 4; ++r) {
        float v = acc[m][n][r] + bn;
        if (OUT_F32) ((float*)Cout)[(gm + r) * (size_t)N + gn] = v;
        else         ((ushort_t*)Cout)[(gm + r) * (size_t)N + gn] = f2bf(v);
      }
    }
  }
}

// ---- fused Q-GEMM + KV-GEMM: 800 uniform 256^2 tiles (640 Q + 160 KV) ----
__global__ __launch_bounds__(512, 2) void gemm_fused_qkv(
    const ushort_t* __restrict__ hbf, const ushort_t* __restrict__ wq,
    const ushort_t* __restrict__ cbf, const ushort_t* __restrict__ wkv,
    const float* __restrict__ bq, const float* __restrict__ bkv,
    ushort_t* __restrict__ qb, ushort_t* __restrict__ kvb) {
  __shared__ ushort_t lds[73728];   // 144 KiB = 9 x 16 KiB
  char* ldsc = (char*)lds;
  const int nwg = 800;              // 800 % 8 == 0 -> bijective XCD swizzle
  int bid = blockIdx.x;
  bid = (bid & 7) * (nwg >> 3) + (bid >> 3);
  if (bid < 640) {
    const int tm = bid / 20, tn = bid % 20;
    const size_t m0 = (size_t)tm * 256, n0 = (size_t)tn * 256;
    gemm_core<0>(hbf + m0 * DIM, wq + n0 * DIM, bq, qb, DIM, m0, n0, ldsc);
  } else {
    const int e = bid - 640;
    const int tm = e / 40, tn = e % 40;
    const size_t m0 = (size_t)tm * 256, n0 = (size_t)tn * 256;
    gemm_core<0>(cbf + m0 * DIM, wkv + n0 * DIM, bkv, kvb, 2 * DIM, m0, n0, ldsc);
  }
}

// ---- output GEMM: 640 tiles, fp32 out ----
__global__ __launch_bounds__(512, 2) void gemm_out(
    const ushort_t* __restrict__ A, const ushort_t* __restrict__ W,
    const float* __restrict__ bias, float* __restrict__ C) {
  __shared__ ushort_t lds[73728];
  char* ldsc = (char*)lds;
  const int nwg = 640;
  int bid = blockIdx.x;
  bid = (bid & 7) * (nwg >> 3) + (bid >> 3);
  const int tm = bid / 20, tn = bid % 20;
  const size_t m0 = (size_t)tm * 256, n0 = (size_t)tn * 256;
  gemm_core<1>(A + m0 * DIM, W + n0 * DIM, bias, C, DIM, m0, n0, ldsc);
}

// ---------------- RMSNorm (in place; optional extra output scale) ----------------
__global__ __launch_bounds__(256) void rmsnorm_rows(ushort_t* __restrict__ x,
                                                    const float* __restrict__ gw,
                                                    int ncols, int stride, float oscale) {
  const int row = blockIdx.x;
  ushort_t* p = x + (size_t)row * stride;
  const int tid = threadIdx.x;
  const int nch = ncols >> 3;
  float ss = 0.f;
  for (int ci = tid; ci < nch; ci += 256) {
    bf16x8 v = *(const bf16x8*)(p + ci * 8);
#pragma unroll
    for (int j = 0; j < 8; ++j) { float f = (float)v[j]; ss += f * f; }
  }
#pragma unroll
  for (int off = 1; off < 64; off <<= 1) ss += __shfl_xor(ss, off);
  __shared__ float sred[4];
  if ((tid & 63) == 0) sred[tid >> 6] = ss;
  __syncthreads();
  float tot = sred[0] + sred[1] + sred[2] + sred[3];
  float inv = rsqrtf(tot / (float)ncols + 1e-6f) * oscale;
  for (int ci = tid; ci < nch; ci += 256) {
    bf16x8 v = *(const bf16x8*)(p + ci * 8);
    bf16x8 ov;
#pragma unroll
    for (int j = 0; j < 8; ++j) {
      float f = (float)v[j];
      ushort_t ob = f2bf(f * inv * gw[ci * 8 + j]);
      ov[j] = *(__bf16*)&ob;
    }
    *(bf16x8*)(p + ci * 8) = ov;
  }
}

// ---------------- V transpose: kv[:, DIM + h*HD + d] -> vt[bh][d][l] ----------------
__global__ __launch_bounds__(256) void transpose_v(const ushort_t* __restrict__ kv,
                                                   ushort_t* __restrict__ vt) {
  const int bh = blockIdx.y, b = bh / NH, h = bh % NH;
  const int l0 = blockIdx.x * 32;
  const ushort_t* src = kv + (size_t)b * L_LEN * (2 * DIM) + DIM + (size_t)h * HD;
  ushort_t* dst = vt + (size_t)bh * HD * L_LEN;
  __shared__ ushort_t tile[32][HD + 16];
  const int tid = threadIdx.x;
#pragma unroll
  for (int i = 0; i < 2; ++i) {
    int gid = i * 256 + tid;
    int r = gid >> 4, ce = (gid & 15) << 3;
    *(bf16x8*)(&tile[r][ce]) = *(const bf16x8*)(src + (size_t)(l0 + r) * (2 * DIM) + ce);
  }
  __syncthreads();
#pragma unroll
  for (int i = 0; i < 2; ++i) {
    int gid = i * 256 + tid;
    int d = gid >> 2, le = (gid & 3) << 3;
    bf16x8 v;
#pragma unroll
    for (int j = 0; j < 8; ++j) v[j] = *(__bf16*)&tile[le + j][d];
    *(bf16x8*)(dst + (size_t)d * L_LEN + l0 + le) = v;
  }
}

// ---------------- fused cross-attention: LDS-staged K/V, swapped-QK^T (R8) ----------
__global__ __launch_bounds__(256) void attn_fwd(const ushort_t* __restrict__ q,
                                                const ushort_t* __restrict__ kv,
                                                const ushort_t* __restrict__ vt,
                                                ushort_t* __restrict__ out) {
  const int bh = blockIdx.y, b = bh / NH, h = bh % NH;
  const int tid = threadIdx.x, w = tid >> 6, lane = tid & 63;
  const int lq = lane & 31, hi = lane >> 5;
  const int qr0 = blockIdx.x * 128 + w * 32;

  __shared__ ushort_t sK[2][4096];   // [buf][16 slabs][32 l][8k]
  __shared__ ushort_t sV[2][4096];   // [buf][4 slabs][128 d][8l]

  const int skl = tid >> 3, skc = tid & 7;
  const ushort_t* kgsrc = kv + ((size_t)b * L_LEN + skl) * (2 * DIM)
                             + (size_t)h * HD + skc * 16;
  ushort_t* kd0 = &sK[0][(skc * 2) * 256 + skl * 8];
  ushort_t* kd1 = &sK[0][(skc * 2 + 1) * 256 + skl * 8];
  const int svd = tid >> 1, svh = tid & 1;
  const ushort_t* vgsrc = vt + (size_t)bh * HD * L_LEN + (size_t)svd * L_LEN + svh * 16;
  ushort_t* vd0 = &sV[0][(svh * 2) * 1024 + svd * 8];
  ushort_t* vd1 = &sV[0][(svh * 2 + 1) * 1024 + svd * 8];

  const ushort_t* qrow = q + ((size_t)b * S_LEN + qr0 + lq) * DIM + (size_t)h * HD + hi * 8;
  bf16x8 qf[8];
#pragma unroll
  for (int ks = 0; ks < 8; ++ks) qf[ks] = *(const bf16x8*)(qrow + ks * 16);

  f32x16 o[4];
#pragma unroll
  for (int ch = 0; ch < 4; ++ch) o[ch] = 0.f;
  float m = -1e30f, lsum = 0.f;

  {
    uint4 ka = *(const uint4*)kgsrc;
    uint4 kb = *(const uint4*)(kgsrc + 8);
    uint4 va = *(const uint4*)vgsrc;
    uint4 vb = *(const uint4*)(vgsrc + 8);
    *(uint4*)kd0 = ka; *(uint4*)kd1 = kb;
    *(uint4*)vd0 = va; *(uint4*)vd1 = vb;
  }
  __syncthreads();

  const int NT = L_LEN / 32;
  int buf = 0;
  for (int t = 0; t < NT; ++t) {
    uint4 ka, kb, va, vb;
    if (t + 1 < NT) {
      const ushort_t* kg = kgsrc + (size_t)(t + 1) * 32 * (2 * DIM);
      const ushort_t* vg = vgsrc + (t + 1) * 32;
      ka = *(const uint4*)kg; kb = *(const uint4*)(kg + 8);
      va = *(const uint4*)vg; vb = *(const uint4*)(vg + 8);
    }

    const ushort_t* kbuf = sK[buf];
    const ushort_t* vbuf = sV[buf];

    f32x16 sv = 0.f;
#pragma unroll
    for (int ks = 0; ks < 8; ++ks) {
      bf16x8 kf = *(const bf16x8*)(kbuf + (ks * 2 + hi) * 256 + lq * 8);
      sv = __builtin_amdgcn_mfma_f32_32x32x16_bf16(kf, qf[ks], sv, 0, 0, 0);
    }
    float pm = fmaxf(fmaxf(fmaxf(sv[0], sv[1]), fmaxf(sv[2], sv[3])),
                     fmaxf(fmaxf(sv[4], sv[5]), fmaxf(sv[6], sv[7])));
    pm = fmaxf(pm, fmaxf(fmaxf(fmaxf(sv[8], sv[9]), fmaxf(sv[10], sv[11])),
                         fmaxf(fmaxf(sv[12], sv[13]), fmaxf(sv[14], sv[15]))));
    pm = fmaxf(pm, __shfl_xor(pm, 32));
    if (__ballot(pm > m + 8.0f)) {
      float mn = fmaxf(m, pm);
      float al = __builtin_amdgcn_exp2f(m - mn);
      lsum *= al;
      m = mn;
#pragma unroll
      for (int r = 0; r < 16; ++r) {
        float ar = __shfl(al, (r & 3) + 8 * (r >> 2) + 4 * hi);
        o[0][r] *= ar; o[1][r] *= ar; o[2][r] *= ar; o[3][r] *= ar;
      }
    }
    float p[16]; float ls = 0.f;
#pragma unroll
    for (int r = 0; r < 16; ++r) { p[r] = __builtin_amdgcn_exp2f(sv[r] - m); ls += p[r]; }
    ls += __shfl_xor(ls, 32);
    lsum += ls;
    bf16x8 pa[2];
#pragma unroll
    for (int ks = 0; ks < 2; ++ks) {
      unsigned w0 = (unsigned)f2bf(p[8 * ks + 0]) | ((unsigned)f2bf(p[8 * ks + 1]) << 16);
      unsigned w1 = (unsigned)f2bf(p[8 * ks + 2]) | ((unsigned)f2bf(p[8 * ks + 3]) << 16);
      unsigned w2 = (unsigned)f2bf(p[8 * ks + 4]) | ((unsigned)f2bf(p[8 * ks + 5]) << 16);
      unsigned w3 = (unsigned)f2bf(p[8 * ks + 6]) | ((unsigned)f2bf(p[8 * ks + 7]) << 16);
      unsigned e0 = __shfl_xor((int)w0, 32), e1 = __shfl_xor((int)w1, 32);
      unsigned e2 = __shfl_xor((int)w2, 32), e3 = __shfl_xor((int)w3, 32);
      unsigned d0 = hi ? e2 : w0, d1 = hi ? e3 : w1;
      unsigned d2 = hi ? w2 : e0, d3 = hi ? w3 : e1;
      unsigned tmp[4] = {d0, d1, d2, d3};
      pa[ks] = *(const bf16x8*)tmp;
    }
#pragma unroll
    for (int ch = 0; ch < 4; ++ch) {
#pragma unroll
      for (int ks = 0; ks < 2; ++ks) {
        bf16x8 vf = *(const bf16x8*)(vbuf + (ks * 2 + hi) * 1024 + (ch * 32 + lq) * 8);
        o[ch] = __builtin_amdgcn_mfma_f32_32x32x16_bf16(pa[ks], vf, o[ch], 0, 0, 0);
      }
    }

    if (t + 1 < NT) {
      const int nb = buf ^ 1;
      *(uint4*)(kd0 + nb * 4096) = ka; *(uint4*)(kd1 + nb * 4096) = kb;
      *(uint4*)(vd0 + nb * 4096) = va; *(uint4*)(vd1 + nb * 4096) = vb;
    }
    __syncthreads();
    buf ^= 1;
  }

  float inv[16];
#pragma unroll
  for (int r = 0; r < 16; ++r) {
    float lr = __shfl(lsum, (r & 3) + 8 * (r >> 2) + 4 * hi);
    inv[r] = 1.0f / lr;
  }
  ushort_t* ob = out + ((size_t)b * S_LEN + qr0) * DIM + (size_t)h * HD;
#pragma unroll
  for (int ch = 0; ch < 4; ++ch)
#pragma unroll
    for (int r = 0; r < 16; ++r) {
      int row = (r & 3) + 8 * (r >> 2) + 4 * hi;
      ob[(size_t)row * DIM + ch * 32 + lq] = f2bf(o[ch][r] * inv[r]);
    }
}

// ---------------- host ----------------
extern "C" void kernel_launch(void* const* d_in, const int* in_sizes, int n_in,
                              void* d_out, int out_size, void* d_ws, size_t ws_size,
                              hipStream_t stream) {
  (void)in_sizes; (void)n_in; (void)out_size; (void)ws_size;
  const float* hidden_c = (const float*)d_in[0];
  const float* hidden_u = (const float*)d_in[1];
  const float* ctx_c    = (const float*)d_in[2];
  const float* ctx_u    = (const float*)d_in[3];
  const float* Wq  = (const float*)d_in[4];
  const float* bq  = (const float*)d_in[5];
  const float* Wkv = (const float*)d_in[6];
  const float* bkv = (const float*)d_in[7];
  const float* gq  = (const float*)d_in[8];
  const float* gk  = (const float*)d_in[9];
  const float* Wo  = (const float*)d_in[10];
  const float* bo  = (const float*)d_in[11];

  char* ws = (char*)d_ws;
  size_t off = 0;
  auto alloc = [&](size_t bytes) {
    char* p = ws + off; off += (bytes + 255) & ~(size_t)255; return p;
  };
  ushort_t* hbf  = (ushort_t*)alloc((size_t)MQ * DIM * 2);
  ushort_t* cbf  = (ushort_t*)alloc((size_t)ML * DIM * 2);
  ushort_t* wqb  = (ushort_t*)alloc((size_t)DIM * DIM * 2);
  ushort_t* wkvb = (ushort_t*)alloc((size_t)2 * DIM * DIM * 2);
  ushort_t* kvb  = (ushort_t*)alloc((size_t)ML * 2 * DIM * 2);
  ushort_t* vtb  = (ushort_t*)alloc((size_t)CBATCH * NH * HD * L_LEN * 2);
  ushort_t* qb   = (ushort_t*)d_out;

  auto cvt = [&](const float* in, ushort_t* o, size_t n) {
    int n4 = (int)(n >> 2);
    cvt_f32_bf16<<<dim3((n4 + 255) / 256), dim3(256), 0, stream>>>(in, o, n4);
  };
  cvt(hidden_c, hbf, (size_t)S_LEN * DIM);
  cvt(hidden_u, hbf + (size_t)S_LEN * DIM, (size_t)S_LEN * DIM);
  cvt(ctx_c, cbf, (size_t)L_LEN * DIM);
  cvt(ctx_u, cbf + (size_t)L_LEN * DIM, (size_t)L_LEN * DIM);
  cvt(Wq, wqb, (size_t)DIM * DIM);
  cvt(Wkv, wkvb, (size_t)2 * DIM * DIM);

  // fused Q-GEMM (640 tiles) + KV-GEMM (160 tiles): 800 uniform 256^2 tiles
  gemm_fused_qkv<<<dim3(800), dim3(512), 0, stream>>>(
      hbf, wqb, cbf, wkvb, bq, bkv, qb, kvb);
  // Wo -> bf16 (reuses wqb; launched after fused gemm in stream order)
  cvt(Wo, wqb, (size_t)DIM * DIM);

  const float qscale = 0.08838834764831845f * 1.4426950408889634f;
  rmsnorm_rows<<<dim3(MQ), dim3(256), 0, stream>>>(qb, gq, DIM, DIM, qscale);
  rmsnorm_rows<<<dim3(ML), dim3(256), 0, stream>>>(kvb, gk, DIM, 2 * DIM, 1.0f);
  transpose_v<<<dim3(L_LEN / 32, CBATCH * NH), dim3(256), 0, stream>>>(kvb, vtb);

  attn_fwd<<<dim3(S_LEN / 128, CBATCH * NH), dim3(256), 0, stream>>>(qb, kvb, vtb, hbf);

  // out = attn_out @ Wo^T + bo -> d_out (fp32)
  gemm_out<<<dim3(640), dim3(512), 0, stream>>>(hbf, wqb, bo, (float*)d_out);
}